// Round 7
// baseline (389.786 us; speedup 1.0000x reference)
//
#include <hip/hip_runtime.h>

#define HID 50
#define IND 8
#define TLEN 512
#define NB 8          // batch columns per block (MFMA N cols 8..15 dead)
#define CH 256        // x chunk timesteps staged in LDS (2 chunks per sequence)
#define BSTR 88       // B row stride in halves (16B-aligned rows, ~2-way banks)
#define NTILE 13      // M rows R = 4*jh + g, jh < 52

typedef _Float16 f16x8 __attribute__((ext_vector_type(8)));
typedef _Float16 f16x4 __attribute__((ext_vector_type(4)));
typedef float f32x4 __attribute__((ext_vector_type(4)));

__device__ __forceinline__ float fast_sigmoid(float v) {
    float e = __builtin_amdgcn_exp2f(-1.44269504f * v);
    return __builtin_amdgcn_rcpf(1.0f + e);
}
__device__ __forceinline__ float fast_tanh(float v) {
    float e = __builtin_amdgcn_exp2f(2.88539008f * v);
    return 1.0f - 2.0f * __builtin_amdgcn_rcpf(e + 1.0f);
}

// Gate-aligned M packing (round-6-verified): A row R = 4*jh + g.
// B k-layout CHANGED: [h(0..49) | zero(50..55) | x_t(56..63)] so quad 3's
// bf1 fragment (k=56..63) is read straight from x_lds — B_lds carries ONLY
// h rows, written once per step by the gate lanes. B is double-buffered:
// read B[t&1], write h(t+1) into B[~t&1], ONE __syncthreads per step.
__global__ __launch_bounds__(256, 2) void gru_mfma3(
    const float* __restrict__ x,      // [B, T, 8]
    const float* __restrict__ W_ih,   // [150, 8]
    const float* __restrict__ W_hh,   // [150, 50]
    const float* __restrict__ b_ih,   // [150]
    const float* __restrict__ b_hh,   // [150]
    const float* __restrict__ W_out,  // [1, 50]
    const float* __restrict__ b_out,  // [1]
    float* __restrict__ out)          // [B]
{
    const int tid  = threadIdx.x;     // 256 threads = 4 waves
    const int wave = tid >> 6;
    const int lane = tid & 63;
    const int m16  = lane & 15;
    const int quad = lane >> 4;
    const int bb   = blockIdx.x;

    __shared__ _Float16 x_lds[CH * NB * IND];    // [t&255][n][d], 32 KB
    __shared__ _Float16 B_lds[2][16 * BSTR];     // [buf][n][k], 5.5 KB
    __shared__ float    red[NB * 56];            // head scratch

    // ---- one-time: A fragments + biases into VGPRs ----
    // A[m=lane&15][k=quad*8+j] (verified). x block now at k=56..63.
    auto aval = [&](int T, int k) -> float {
        const int R  = 16 * T + m16;
        const int jh = R >> 2;
        const int g  = R & 3;
        if (jh >= HID) return 0.f;
        if (g <= 1) {
            if (k < HID) return W_hh[(g * HID + jh) * HID + k];
            if (k >= 56) return W_ih[(g * HID + jh) * IND + (k - 56)];
            return 0.f;
        }
        if (g == 2) return (k < HID) ? W_hh[(2 * HID + jh) * HID + k] : 0.f;
        return (k >= 56) ? W_ih[(2 * HID + jh) * IND + (k - 56)] : 0.f;
    };

    f16x8 a0[4], a1[4];
    f32x4 bias[4];
    float h[4] = {0.f, 0.f, 0.f, 0.f};
#pragma unroll
    for (int tt = 0; tt < 4; ++tt) {
        const int T = wave + 4 * tt;
        if (T < NTILE) {
#pragma unroll
            for (int j = 0; j < 8; ++j) {
                a0[tt][j] = (_Float16)aval(T, quad * 8 + j);
                a1[tt][j] = (_Float16)aval(T, 32 + quad * 8 + j);
            }
            const int jh = 4 * T + quad;
#pragma unroll
            for (int r = 0; r < 4; ++r) {
                float v = 0.f;
                if (jh < HID) {
                    if (r == 0)      v = b_ih[jh] + b_hh[jh];
                    else if (r == 1) v = b_ih[HID + jh] + b_hh[HID + jh];
                    else if (r == 2) v = b_hh[2 * HID + jh];
                    else             v = b_ih[2 * HID + jh];
                }
                bias[tt][r] = v;
            }
        } else {
#pragma unroll
            for (int j = 0; j < 8; ++j) { a0[tt][j] = (_Float16)0.f; a1[tt][j] = (_Float16)0.f; }
            bias[tt] = f32x4{0.f, 0.f, 0.f, 0.f};
        }
    }

    // ---- x chunk staging: 256 timesteps -> 32 KB fp16 (16 float4/thread) ----
    auto stage_chunk = [&](int c) {
        const float* xb = x + (size_t)bb * NB * TLEN * IND + (size_t)c * CH * IND;
#pragma unroll
        for (int r = 0; r < 16; ++r) {
            const int f    = tid + 256 * r;          // 0..4095
            const int n    = f >> 9;                 // 0..7
            const int rem  = f & 511;
            const int trel = rem >> 1;
            const int d    = (rem & 1) * 4;
            const float4 v = ((const float4*)(xb + (size_t)n * TLEN * IND))[rem];
            *(f16x4*)&x_lds[trel * (NB * IND) + n * IND + d] =
                f16x4{(_Float16)v.x, (_Float16)v.y, (_Float16)v.z, (_Float16)v.w};
        }
    };

    // ---- init: zero both B buffers (h_{-1}=0; pad rows stay 0 forever) ----
    for (int idx = tid; idx < 2 * 16 * BSTR; idx += 256)
        B_lds[0][idx] = (_Float16)0.f;   // flat over both buffers
    stage_chunk(0);
    __syncthreads();

    for (int t = 0; t < TLEN; ++t) {
        const int cur = t & 1, nxt = cur ^ 1;

        // restage second x chunk exactly once (uniform branch, t=256)
        if (t == CH) {
            stage_chunk(1);
            __syncthreads();
        }

        // B(t) fragments. bf0: k=quad*8 (h rows 0..31). bf1: quads 0-2 from
        // B_lds (k=32..55: h + zeros), quad 3 from x_lds (x_t = k 56..63).
        const f16x8 bf0 = *(const f16x8*)&B_lds[cur][m16 * BSTR + quad * 8];
        const _Float16* bf1p = (quad == 3)
            ? &x_lds[(t & (CH - 1)) * (NB * IND) + m16 * IND]
            : &B_lds[cur][m16 * BSTR + 32 + quad * 8];
        const f16x8 bf1 = *(const f16x8*)bf1p;

        f32x4 c[4];
#pragma unroll
        for (int tt = 0; tt < 4; ++tt) {
            if (wave + 4 * tt < NTILE) {
                c[tt] = __builtin_amdgcn_mfma_f32_16x16x32_f16(a0[tt], bf0, bias[tt], 0, 0, 0);
                c[tt] = __builtin_amdgcn_mfma_f32_16x16x32_f16(a1[tt], bf1, c[tt],   0, 0, 0);
            }
        }

        // gates in-register; h(t+1) written into the OTHER B buffer
#pragma unroll
        for (int tt = 0; tt < 4; ++tt) {
            const int T = wave + 4 * tt;
            if (T < NTILE) {
                const int jh = 4 * T + quad;
                const float r  = fast_sigmoid(c[tt][0]);
                const float z  = fast_sigmoid(c[tt][1]);
                const float nn = fast_tanh(c[tt][3] + r * c[tt][2]);
                h[tt] = nn + z * (h[tt] - nn);
                if (m16 < NB && jh < HID)
                    B_lds[nxt][m16 * BSTR + jh] = (_Float16)h[tt];
            }
        }

        __syncthreads();   // the ONLY per-step barrier: h(t+1) visible
    }

    // ---- head: out[n] = sum_jh h(jh,n) * W_out[jh] + b_out ----
#pragma unroll
    for (int tt = 0; tt < 4; ++tt) {
        const int T = wave + 4 * tt;
        if (T < NTILE) {
            const int jh = 4 * T + quad;
            if (m16 < NB && jh < HID)
                red[m16 * 56 + jh] = h[tt] * W_out[jh];
        }
    }
    __syncthreads();
    if (tid < NB) {
        float s = b_out[0];
        for (int j = 0; j < HID; ++j) s += red[tid * 56 + j];
        out[bb * NB + tid] = s;
    }
}

extern "C" void kernel_launch(void* const* d_in, const int* in_sizes, int n_in,
                              void* d_out, int out_size, void* d_ws, size_t ws_size,
                              hipStream_t stream) {
    const float* x     = (const float*)d_in[0];
    const float* W_ih  = (const float*)d_in[1];
    const float* W_hh  = (const float*)d_in[2];
    const float* b_ih  = (const float*)d_in[3];
    const float* b_hh  = (const float*)d_in[4];
    const float* W_out = (const float*)d_in[5];
    const float* b_out = (const float*)d_in[6];
    float* out = (float*)d_out;

    const int B = in_sizes[0] / (TLEN * IND);   // 4096
    gru_mfma3<<<B / NB, 256, 0, stream>>>(x, W_ih, W_hh, b_ih, b_hh, W_out, b_out, out);
}

// Round 8
// 289.032 us; speedup vs baseline: 1.3486x; 1.3486x over previous
//
#include <hip/hip_runtime.h>

#define HID 50
#define IND 8
#define TLEN 512
#define NB 16         // batch columns per block — all 16 MFMA N cols real
#define CH 128        // x chunk timesteps staged in LDS (4 chunks/sequence)
#define XSTR 1032     // x_lds per-column stride in halves (128*8 + 8 pad; 16B-aligned)
#define BSTR 88       // B row stride in halves (16B-aligned rows)
#define NTILE 13      // M rows R = 4*jh + g, jh < 52

typedef _Float16 f16x8 __attribute__((ext_vector_type(8)));
typedef _Float16 f16x4 __attribute__((ext_vector_type(4)));
typedef float f32x4 __attribute__((ext_vector_type(4)));

__device__ __forceinline__ float fast_sigmoid(float v) {
    float e = __builtin_amdgcn_exp2f(-1.44269504f * v);
    return __builtin_amdgcn_rcpf(1.0f + e);
}
__device__ __forceinline__ float fast_tanh(float v) {
    float e = __builtin_amdgcn_exp2f(2.88539008f * v);
    return 1.0f - 2.0f * __builtin_amdgcn_rcpf(e + 1.0f);
}

// Round-8 = round-5's lane-efficient N=16 shape + round-6/7 machinery:
//  - gate-aligned M packing (A row R = 4*jh + g), gates fully in-register
//  - B k-layout [h(0..49) | 0(50..55) | x_t(56..63)]: quad 3's bf1 fragment
//    comes straight from x_lds; B_lds carries only h rows
//  - B double-buffered, ONE __syncthreads per step
//  - x_lds per-column contiguous (bank-conflict fix for staging writes)
// 8 waves: wave w owns tiles T = w and w+8 (T<13). 512 threads, grid=256.
__global__ __launch_bounds__(512, 2) void gru_mfma4(
    const float* __restrict__ x,      // [B, T, 8]
    const float* __restrict__ W_ih,   // [150, 8]
    const float* __restrict__ W_hh,   // [150, 50]
    const float* __restrict__ b_ih,   // [150]
    const float* __restrict__ b_hh,   // [150]
    const float* __restrict__ W_out,  // [1, 50]
    const float* __restrict__ b_out,  // [1]
    float* __restrict__ out)          // [B]
{
    const int tid  = threadIdx.x;     // 512 threads = 8 waves
    const int wave = tid >> 6;
    const int lane = tid & 63;
    const int m16  = lane & 15;
    const int quad = lane >> 4;
    const int bb   = blockIdx.x;

    __shared__ _Float16 x_lds[NB * XSTR];       // [n][trel*8+d], 33 KB
    __shared__ _Float16 B_lds[2][16 * BSTR];    // [buf][n][k], 5.6 KB
    __shared__ float    red[NB * 56];           // head scratch, 3.5 KB

    // ---- one-time: A fragments + biases into VGPRs ----
    // A[m=lane&15][k=quad*8+j] (HW-verified). x block at k=56..63.
    auto aval = [&](int T, int k) -> float {
        const int R  = 16 * T + m16;
        const int jh = R >> 2;
        const int g  = R & 3;
        if (jh >= HID) return 0.f;
        if (g <= 1) {
            if (k < HID) return W_hh[(g * HID + jh) * HID + k];
            if (k >= 56) return W_ih[(g * HID + jh) * IND + (k - 56)];
            return 0.f;
        }
        if (g == 2) return (k < HID) ? W_hh[(2 * HID + jh) * HID + k] : 0.f;
        return (k >= 56) ? W_ih[(2 * HID + jh) * IND + (k - 56)] : 0.f;
    };

    f16x8 a0[2], a1[2];
    f32x4 bias[2];
    float h[2] = {0.f, 0.f};
#pragma unroll
    for (int tt = 0; tt < 2; ++tt) {
        const int T = wave + 8 * tt;
        if (T < NTILE) {
#pragma unroll
            for (int j = 0; j < 8; ++j) {
                a0[tt][j] = (_Float16)aval(T, quad * 8 + j);
                a1[tt][j] = (_Float16)aval(T, 32 + quad * 8 + j);
            }
            const int jh = 4 * T + quad;
#pragma unroll
            for (int r = 0; r < 4; ++r) {
                float v = 0.f;
                if (jh < HID) {
                    if (r == 0)      v = b_ih[jh] + b_hh[jh];
                    else if (r == 1) v = b_ih[HID + jh] + b_hh[HID + jh];
                    else if (r == 2) v = b_hh[2 * HID + jh];
                    else             v = b_ih[2 * HID + jh];
                }
                bias[tt][r] = v;
            }
        } else {
#pragma unroll
            for (int j = 0; j < 8; ++j) { a0[tt][j] = (_Float16)0.f; a1[tt][j] = (_Float16)0.f; }
            bias[tt] = f32x4{0.f, 0.f, 0.f, 0.f};
        }
    }

    // ---- x chunk staging: 128 timesteps, per-column contiguous ----
    // 32 threads per column; global: consecutive threads read consecutive
    // float4 (coalesced); LDS: consecutive lanes write contiguous 8B
    // (conflict-free). Layout: x_lds[n*XSTR + trel*8 + d].
    auto stage_chunk = [&](int c) {
        const int n = tid >> 5;        // 0..15
        const int s = tid & 31;
        const float4* src = (const float4*)(x + ((size_t)(bb * NB + n) * TLEN + (size_t)c * CH) * IND);
#pragma unroll
        for (int r = 0; r < 8; ++r) {
            const int fidx = s + 32 * r;          // 0..255 float4 per column
            const float4 v = src[fidx];
            const int trel = fidx >> 1;
            const int d    = (fidx & 1) * 4;
            *(f16x4*)&x_lds[n * XSTR + trel * 8 + d] =
                f16x4{(_Float16)v.x, (_Float16)v.y, (_Float16)v.z, (_Float16)v.w};
        }
    };

    // ---- init: zero both B buffers; stage chunk 0 ----
    for (int idx = tid; idx < 2 * 16 * BSTR; idx += 512)
        B_lds[0][idx] = (_Float16)0.f;           // flat across both buffers
    stage_chunk(0);
    __syncthreads();

    for (int t = 0; t < TLEN; ++t) {
        const int cur = t & 1, nxt = cur ^ 1;

        // restage x every 128 steps (t = 128, 256, 384; uniform branch)
        if ((t & (CH - 1)) == 0 && t != 0) {
            stage_chunk(t >> 7);
            __syncthreads();
        }

        // B(t) fragments [B[k=quad*8+j][n=m16]]: bf0 = h rows 0..31;
        // bf1 = quads 0-2 from B_lds (h 32..49 + zeros), quad 3 = x_t from x_lds.
        const f16x8 bf0 = *(const f16x8*)&B_lds[cur][m16 * BSTR + quad * 8];
        const _Float16* bf1p = (quad == 3)
            ? &x_lds[m16 * XSTR + (t & (CH - 1)) * 8]
            : &B_lds[cur][m16 * BSTR + 32 + quad * 8];
        const f16x8 bf1 = *(const f16x8*)bf1p;

        f32x4 c[2];
#pragma unroll
        for (int tt = 0; tt < 2; ++tt) {
            if (wave + 8 * tt < NTILE) {
                c[tt] = __builtin_amdgcn_mfma_f32_16x16x32_f16(a0[tt], bf0, bias[tt], 0, 0, 0);
                c[tt] = __builtin_amdgcn_mfma_f32_16x16x32_f16(a1[tt], bf1, c[tt],   0, 0, 0);
            }
        }

        // gates in-register; h(t+1) written into the other B buffer
#pragma unroll
        for (int tt = 0; tt < 2; ++tt) {
            const int T = wave + 8 * tt;
            if (T < NTILE) {
                const int jh = 4 * T + quad;
                const float r  = fast_sigmoid(c[tt][0]);
                const float z  = fast_sigmoid(c[tt][1]);
                const float nn = fast_tanh(c[tt][3] + r * c[tt][2]);
                h[tt] = nn + z * (h[tt] - nn);
                if (jh < HID)
                    B_lds[nxt][m16 * BSTR + jh] = (_Float16)h[tt];
            }
        }

        __syncthreads();   // the only per-step barrier: h(t+1) visible
    }

    // ---- head: out[n] = sum_jh h(jh,n) * W_out[jh] + b_out ----
#pragma unroll
    for (int tt = 0; tt < 2; ++tt) {
        const int T = wave + 8 * tt;
        if (T < NTILE) {
            const int jh = 4 * T + quad;
            if (jh < HID)
                red[m16 * 56 + jh] = h[tt] * W_out[jh];
        }
    }
    __syncthreads();
    if (tid < NB) {
        float s = b_out[0];
        for (int j = 0; j < HID; ++j) s += red[tid * 56 + j];
        out[bb * NB + tid] = s;
    }
}

extern "C" void kernel_launch(void* const* d_in, const int* in_sizes, int n_in,
                              void* d_out, int out_size, void* d_ws, size_t ws_size,
                              hipStream_t stream) {
    const float* x     = (const float*)d_in[0];
    const float* W_ih  = (const float*)d_in[1];
    const float* W_hh  = (const float*)d_in[2];
    const float* b_ih  = (const float*)d_in[3];
    const float* b_hh  = (const float*)d_in[4];
    const float* W_out = (const float*)d_in[5];
    const float* b_out = (const float*)d_in[6];
    float* out = (float*)d_out;

    const int B = in_sizes[0] / (TLEN * IND);   // 4096
    gru_mfma4<<<B / NB, 512, 0, stream>>>(x, W_ih, W_hh, b_ih, b_hh, W_out, b_out, out);
}

// Round 9
// 265.213 us; speedup vs baseline: 1.4697x; 1.0898x over previous
//
#include <hip/hip_runtime.h>

#define HID 50
#define IND 8
#define TLEN 512
#define NB 16         // batch columns per block — all 16 MFMA N cols real
#define CH 128        // x chunk timesteps staged in LDS (4 chunks/sequence)
#define XSTR 1032     // x_lds per-column stride in halves
#define BSTR 88       // B row stride in halves (16B-aligned rows)
#define NTILE 13      // M rows R = 4*jh + g, jh < 52; tile T owned by wave T

typedef _Float16 f16x8 __attribute__((ext_vector_type(8)));
typedef _Float16 f16x4 __attribute__((ext_vector_type(4)));
typedef float f32x4 __attribute__((ext_vector_type(4)));

__device__ __forceinline__ float fast_sigmoid(float v) {
    float e = __builtin_amdgcn_exp2f(-1.44269504f * v);
    return __builtin_amdgcn_rcpf(1.0f + e);
}
__device__ __forceinline__ float fast_tanh(float v) {
    float e = __builtin_amdgcn_exp2f(2.88539008f * v);
    return 1.0f - 2.0f * __builtin_amdgcn_rcpf(e + 1.0f);
}

// Round-9: 13 waves (832 threads), ONE M-tile per wave — shortest possible
// per-wave chain; ~3.25 waves/SIMD interleave the read/MFMA/gate phases.
// Split accumulators break the 2-MFMA serial dependency. Everything else
// is round-8 machinery: gate-aligned M packing (R=4*jh+g), in-register
// gates + fp32 h, double-buffered B (one barrier/step), B k-layout
// [h(0..49)|0(50..55)|x_t(56..63)] with quad 3 reading x_lds directly.
__global__ __launch_bounds__(832, 1) void gru_mfma5(
    const float* __restrict__ x,      // [B, T, 8]
    const float* __restrict__ W_ih,   // [150, 8]
    const float* __restrict__ W_hh,   // [150, 50]
    const float* __restrict__ b_ih,   // [150]
    const float* __restrict__ b_hh,   // [150]
    const float* __restrict__ W_out,  // [1, 50]
    const float* __restrict__ b_out,  // [1]
    float* __restrict__ out)          // [B]
{
    const int tid  = threadIdx.x;     // 832 threads = 13 waves
    const int wave = tid >> 6;        // == tile T, 0..12
    const int lane = tid & 63;
    const int m16  = lane & 15;
    const int quad = lane >> 4;
    const int bb   = blockIdx.x;
    const int jh   = 4 * wave + quad; // this lane's hidden unit (0..51)

    __shared__ _Float16 x_lds[NB * XSTR];       // [n][trel*8+d], 33 KB
    __shared__ _Float16 B_lds[2][16 * BSTR];    // [buf][n][k], 5.6 KB
    __shared__ float    red[NB * 56];           // head scratch, 3.5 KB

    // ---- one-time: A fragments + biases into VGPRs ----
    // A[m=lane&15][k=quad*8+j] (HW-verified). x block at k=56..63.
    auto aval = [&](int k) -> float {
        const int R  = 16 * wave + m16;
        const int rj = R >> 2;
        const int g  = R & 3;
        if (rj >= HID) return 0.f;
        if (g <= 1) {
            if (k < HID) return W_hh[(g * HID + rj) * HID + k];
            if (k >= 56) return W_ih[(g * HID + rj) * IND + (k - 56)];
            return 0.f;
        }
        if (g == 2) return (k < HID) ? W_hh[(2 * HID + rj) * HID + k] : 0.f;
        return (k >= 56) ? W_ih[(2 * HID + rj) * IND + (k - 56)] : 0.f;
    };

    f16x8 a0, a1;
#pragma unroll
    for (int j = 0; j < 8; ++j) {
        a0[j] = (_Float16)aval(quad * 8 + j);
        a1[j] = (_Float16)aval(32 + quad * 8 + j);
    }
    f32x4 bias;
#pragma unroll
    for (int r = 0; r < 4; ++r) {
        float v = 0.f;
        if (jh < HID) {
            if (r == 0)      v = b_ih[jh] + b_hh[jh];
            else if (r == 1) v = b_ih[HID + jh] + b_hh[HID + jh];
            else if (r == 2) v = b_hh[2 * HID + jh];
            else             v = b_ih[2 * HID + jh];
        }
        bias[r] = v;
    }
    const f32x4 zero4 = {0.f, 0.f, 0.f, 0.f};
    float h = 0.f;

    // ---- x chunk staging: 128 timesteps, per-column contiguous ----
    auto stage_chunk = [&](int c) {
        if (tid < 512) {
            const int n = tid >> 5;    // 0..15
            const int s = tid & 31;
            const float4* src = (const float4*)(x + ((size_t)(bb * NB + n) * TLEN + (size_t)c * CH) * IND);
#pragma unroll
            for (int r = 0; r < 8; ++r) {
                const int fidx = s + 32 * r;      // 0..255 float4 per column
                const float4 v = src[fidx];
                const int trel = fidx >> 1;
                const int d    = (fidx & 1) * 4;
                *(f16x4*)&x_lds[n * XSTR + trel * 8 + d] =
                    f16x4{(_Float16)v.x, (_Float16)v.y, (_Float16)v.z, (_Float16)v.w};
            }
        }
    };

    // ---- init: zero both B buffers; stage chunk 0 ----
    for (int idx = tid; idx < 2 * 16 * BSTR; idx += 832)
        B_lds[0][idx] = (_Float16)0.f;            // flat across both buffers
    stage_chunk(0);
    __syncthreads();

    // ---- the recurrence: one tile per wave, one barrier per step ----
    auto step = [&](int t, int cur, int nxt) {
        // B(t) fragments [B[k=quad*8+j][n=m16]]
        const f16x8 bf0 = *(const f16x8*)&B_lds[cur][m16 * BSTR + quad * 8];
        const _Float16* bf1p = (quad == 3)
            ? &x_lds[m16 * XSTR + (t & (CH - 1)) * 8]
            : &B_lds[cur][m16 * BSTR + 32 + quad * 8];
        const f16x8 bf1 = *(const f16x8*)bf1p;

        // independent accumulators (no MFMA->MFMA serial dep)
        const f32x4 c = __builtin_amdgcn_mfma_f32_16x16x32_f16(a0, bf0, bias,  0, 0, 0);
        const f32x4 d = __builtin_amdgcn_mfma_f32_16x16x32_f16(a1, bf1, zero4, 0, 0, 0);

        const float r  = fast_sigmoid(c[0] + d[0]);
        const float z  = fast_sigmoid(c[1] + d[1]);
        const float nn = fast_tanh((c[3] + d[3]) + r * (c[2] + d[2]));
        h = nn + z * (h - nn);
        if (jh < HID)
            B_lds[nxt][m16 * BSTR + jh] = (_Float16)h;
        __syncthreads();   // the only per-step barrier
    };

    for (int t2 = 0; t2 < TLEN; t2 += 2) {
        // restage x every 128 steps (t2 = 128, 256, 384 — all even)
        if ((t2 & (CH - 1)) == 0 && t2 != 0) {
            stage_chunk(t2 >> 7);
            __syncthreads();
        }
        step(t2,     0, 1);
        step(t2 + 1, 1, 0);
    }

    // ---- head: out[n] = sum_jh h(jh,n) * W_out[jh] + b_out ----
    if (jh < HID)
        red[m16 * 56 + jh] = h * W_out[jh];
    __syncthreads();
    if (tid < NB) {
        float s = b_out[0];
        for (int j = 0; j < HID; ++j) s += red[tid * 56 + j];
        out[bb * NB + tid] = s;
    }
}

extern "C" void kernel_launch(void* const* d_in, const int* in_sizes, int n_in,
                              void* d_out, int out_size, void* d_ws, size_t ws_size,
                              hipStream_t stream) {
    const float* x     = (const float*)d_in[0];
    const float* W_ih  = (const float*)d_in[1];
    const float* W_hh  = (const float*)d_in[2];
    const float* b_ih  = (const float*)d_in[3];
    const float* b_hh  = (const float*)d_in[4];
    const float* W_out = (const float*)d_in[5];
    const float* b_out = (const float*)d_in[6];
    float* out = (float*)d_out;

    const int B = in_sizes[0] / (TLEN * IND);   // 4096
    gru_mfma5<<<B / NB, 832, 0, stream>>>(x, W_ih, W_hh, b_ih, b_hh, W_out, b_out, out);
}

// Round 10
// 264.397 us; speedup vs baseline: 1.4742x; 1.0031x over previous
//
#include <hip/hip_runtime.h>

#define HID 50
#define IND 8
#define TLEN 512
#define NB 16         // batch columns per block — all 16 MFMA N cols real
#define CH 128        // x chunk timesteps staged in LDS (4 chunks/sequence)
#define XSTR 1032     // x_lds per-column stride in halves (2064B = 516 dw = 4 mod 32: 2-way)
#define BSTR 72       // B row stride in halves: 144B = 36 dw = 4 (mod 32) -> clean 2-way
                      // banks for bf0/bf1 reads and h writes (88 gave 4-way: 1.7e7 conflicts)
#define NTILE 13      // M rows R = 4*jh + g, jh < 52; tile T owned by wave T

typedef _Float16 f16x8 __attribute__((ext_vector_type(8)));
typedef _Float16 f16x4 __attribute__((ext_vector_type(4)));
typedef float f32x4 __attribute__((ext_vector_type(4)));

__device__ __forceinline__ float fast_sigmoid(float v) {
    float e = __builtin_amdgcn_exp2f(-1.44269504f * v);
    return __builtin_amdgcn_rcpf(1.0f + e);
}
__device__ __forceinline__ float fast_tanh(float v) {
    float e = __builtin_amdgcn_exp2f(2.88539008f * v);
    return 1.0f - 2.0f * __builtin_amdgcn_rcpf(e + 1.0f);
}

// Round-10 = round-9 (13 waves, one M-tile per wave, gate-aligned packing,
// in-register gates + fp32 h, double-buffered B, one barrier/step, quad-3
// reads x_t directly from x_lds) + bank-clean BSTR=72.
__global__ __launch_bounds__(832, 1) void gru_mfma6(
    const float* __restrict__ x,      // [B, T, 8]
    const float* __restrict__ W_ih,   // [150, 8]
    const float* __restrict__ W_hh,   // [150, 50]
    const float* __restrict__ b_ih,   // [150]
    const float* __restrict__ b_hh,   // [150]
    const float* __restrict__ W_out,  // [1, 50]
    const float* __restrict__ b_out,  // [1]
    float* __restrict__ out)          // [B]
{
    const int tid  = threadIdx.x;     // 832 threads = 13 waves
    const int wave = tid >> 6;        // == tile T, 0..12
    const int lane = tid & 63;
    const int m16  = lane & 15;
    const int quad = lane >> 4;
    const int bb   = blockIdx.x;
    const int jh   = 4 * wave + quad; // this lane's hidden unit (0..51)

    __shared__ _Float16 x_lds[NB * XSTR];       // [n][trel*8+d], 33 KB
    __shared__ _Float16 B_lds[2][16 * BSTR];    // [buf][n][k], 4.6 KB
    __shared__ float    red[NB * 56];           // head scratch, 3.5 KB

    // ---- one-time: A fragments + biases into VGPRs ----
    // A[m=lane&15][k=quad*8+j] (HW-verified). x block at k=56..63.
    auto aval = [&](int k) -> float {
        const int R  = 16 * wave + m16;
        const int rj = R >> 2;
        const int g  = R & 3;
        if (rj >= HID) return 0.f;
        if (g <= 1) {
            if (k < HID) return W_hh[(g * HID + rj) * HID + k];
            if (k >= 56) return W_ih[(g * HID + rj) * IND + (k - 56)];
            return 0.f;
        }
        if (g == 2) return (k < HID) ? W_hh[(2 * HID + rj) * HID + k] : 0.f;
        return (k >= 56) ? W_ih[(2 * HID + rj) * IND + (k - 56)] : 0.f;
    };

    f16x8 a0, a1;
#pragma unroll
    for (int j = 0; j < 8; ++j) {
        a0[j] = (_Float16)aval(quad * 8 + j);
        a1[j] = (_Float16)aval(32 + quad * 8 + j);
    }
    f32x4 bias;
#pragma unroll
    for (int r = 0; r < 4; ++r) {
        float v = 0.f;
        if (jh < HID) {
            if (r == 0)      v = b_ih[jh] + b_hh[jh];
            else if (r == 1) v = b_ih[HID + jh] + b_hh[HID + jh];
            else if (r == 2) v = b_hh[2 * HID + jh];
            else             v = b_ih[2 * HID + jh];
        }
        bias[r] = v;
    }
    const f32x4 zero4 = {0.f, 0.f, 0.f, 0.f};
    float h = 0.f;

    // ---- x chunk staging: 128 timesteps, per-column contiguous ----
    auto stage_chunk = [&](int c) {
        if (tid < 512) {
            const int n = tid >> 5;    // 0..15
            const int s = tid & 31;
            const float4* src = (const float4*)(x + ((size_t)(bb * NB + n) * TLEN + (size_t)c * CH) * IND);
#pragma unroll
            for (int r = 0; r < 8; ++r) {
                const int fidx = s + 32 * r;      // 0..255 float4 per column
                const float4 v = src[fidx];
                const int trel = fidx >> 1;
                const int d    = (fidx & 1) * 4;
                *(f16x4*)&x_lds[n * XSTR + trel * 8 + d] =
                    f16x4{(_Float16)v.x, (_Float16)v.y, (_Float16)v.z, (_Float16)v.w};
            }
        }
    };

    // ---- init: zero both B buffers; stage chunk 0 ----
    for (int idx = tid; idx < 2 * 16 * BSTR; idx += 832)
        B_lds[0][idx] = (_Float16)0.f;            // flat across both buffers
    stage_chunk(0);
    __syncthreads();

    // ---- the recurrence: one tile per wave, one barrier per step ----
    auto step = [&](int t, int cur, int nxt) {
        // B(t) fragments [B[k=quad*8+j][n=m16]]
        const f16x8 bf0 = *(const f16x8*)&B_lds[cur][m16 * BSTR + quad * 8];
        const _Float16* bf1p = (quad == 3)
            ? &x_lds[m16 * XSTR + (t & (CH - 1)) * 8]
            : &B_lds[cur][m16 * BSTR + 32 + quad * 8];
        const f16x8 bf1 = *(const f16x8*)bf1p;

        // independent accumulators (no MFMA->MFMA serial dep)
        const f32x4 c = __builtin_amdgcn_mfma_f32_16x16x32_f16(a0, bf0, bias,  0, 0, 0);
        const f32x4 d = __builtin_amdgcn_mfma_f32_16x16x32_f16(a1, bf1, zero4, 0, 0, 0);

        const float r  = fast_sigmoid(c[0] + d[0]);
        const float z  = fast_sigmoid(c[1] + d[1]);
        const float nn = fast_tanh((c[3] + d[3]) + r * (c[2] + d[2]));
        h = nn + z * (h - nn);
        if (jh < HID)
            B_lds[nxt][m16 * BSTR + jh] = (_Float16)h;   // rows 50..55 stay 0
        __syncthreads();   // the only per-step barrier
    };

    for (int t2 = 0; t2 < TLEN; t2 += 2) {
        // restage x every 128 steps (t2 = 128, 256, 384 — all even)
        if ((t2 & (CH - 1)) == 0 && t2 != 0) {
            stage_chunk(t2 >> 7);
            __syncthreads();
        }
        step(t2,     0, 1);
        step(t2 + 1, 1, 0);
    }

    // ---- head: out[n] = sum_jh h(jh,n) * W_out[jh] + b_out ----
    if (jh < HID)
        red[m16 * 56 + jh] = h * W_out[jh];
    __syncthreads();
    if (tid < NB) {
        float s = b_out[0];
        for (int j = 0; j < HID; ++j) s += red[tid * 56 + j];
        out[bb * NB + tid] = s;
    }
}

extern "C" void kernel_launch(void* const* d_in, const int* in_sizes, int n_in,
                              void* d_out, int out_size, void* d_ws, size_t ws_size,
                              hipStream_t stream) {
    const float* x     = (const float*)d_in[0];
    const float* W_ih  = (const float*)d_in[1];
    const float* W_hh  = (const float*)d_in[2];
    const float* b_ih  = (const float*)d_in[3];
    const float* b_hh  = (const float*)d_in[4];
    const float* W_out = (const float*)d_in[5];
    const float* b_out = (const float*)d_in[6];
    float* out = (float*)d_out;

    const int B = in_sizes[0] / (TLEN * IND);   // 4096
    gru_mfma6<<<B / NB, 832, 0, stream>>>(x, W_ih, W_hh, b_ih, b_hh, W_out, b_out, out);
}